// Round 3
// baseline (340.239 us; speedup 1.0000x reference)
//
#include <hip/hip_runtime.h>
#include <stdint.h>

#define TSTEPS 512
#define BATCH 8
#define DM 1024
#define DK 64
#define MROWS (TSTEPS*BATCH)   // 4096
#define NCAT 2176              // 1024 key | 1024 decay | 64 value | 64 query
#define NCHUNK 16
#define CLEN 32                // 512/16

typedef __attribute__((ext_vector_type(8))) __bf16 bf16x8;
typedef __attribute__((ext_vector_type(4))) float f32x4;

__device__ __forceinline__ unsigned short f2bf(float f) {
  unsigned int u = __float_as_uint(f);
  u += 0x7fffu + ((u >> 16) & 1u);
  return (unsigned short)(u >> 16);
}

// ---------------- unified prep kernel ----------------
// grid layout (1-D, 256 threads each):
//   [0,2048)      convert x -> bf16 (8 elems/thread)
//   [2048,3072)   transpose Wk  (32x32 tiles, rowOff 0)
//   [3072,4096)   transpose Wd  (rowOff 1024)
//   [4096,4160)   transpose Wv  (rowOff 2048)
//   [4160,4224)   transpose Wq  (rowOff 2112)
//   [4224,4233)   bias concat
__global__ __launch_bounds__(256) void k_prep(const float* __restrict__ x,
                                              ushort* __restrict__ xb,
                                              const float* __restrict__ Wk,
                                              const float* __restrict__ Wd,
                                              const float* __restrict__ Wv,
                                              const float* __restrict__ Wq,
                                              ushort* __restrict__ Wcat,
                                              const float* __restrict__ bk,
                                              const float* __restrict__ bdc,
                                              const float* __restrict__ bv,
                                              const float* __restrict__ bq,
                                              float* __restrict__ biasc) {
  __shared__ float s[32][33];
  int bid = blockIdx.x, tid = threadIdx.x;
  if (bid < 2048) {
    int i = bid * 256 + tid;             // 524288 total
    const float4* x4 = (const float4*)x;
    float4 a = x4[2*i], b = x4[2*i+1];
    union { ushort ss[8]; uint4 v; } o;
    o.ss[0]=f2bf(a.x); o.ss[1]=f2bf(a.y); o.ss[2]=f2bf(a.z); o.ss[3]=f2bf(a.w);
    o.ss[4]=f2bf(b.x); o.ss[5]=f2bf(b.y); o.ss[6]=f2bf(b.z); o.ss[7]=f2bf(b.w);
    ((uint4*)xb)[i] = o.v;
    return;
  }
  if (bid < 4224) {
    const float* src; int rel, lg, rowOff;
    size_t N;
    if (bid < 3072)      { src = Wk; N = 1024; lg = 5; rowOff = 0;    rel = bid - 2048; }
    else if (bid < 4096) { src = Wd; N = 1024; lg = 5; rowOff = 1024; rel = bid - 3072; }
    else if (bid < 4160) { src = Wv; N = 64;   lg = 1; rowOff = 2048; rel = bid - 4096; }
    else                 { src = Wq; N = 64;   lg = 1; rowOff = 2112; rel = bid - 4160; }
    int n0 = (rel & ((1 << lg) - 1)) << 5;
    int k0 = (rel >> lg) << 5;
    int tx = tid & 31, ty = tid >> 5;    // 32 x 8
    for (int i = 0; i < 4; ++i)
      s[ty + 8*i][tx] = src[(size_t)(k0 + ty + 8*i) * N + n0 + tx];
    __syncthreads();
    for (int i = 0; i < 4; ++i)
      Wcat[(size_t)(n0 + ty + 8*i + rowOff) * 1024 + k0 + tx] = f2bf(s[tx][ty + 8*i]);
    return;
  }
  int n = (bid - 4224) * 256 + tid;
  if (n >= NCAT) return;
  float v;
  if (n < 1024)      v = bk[n];
  else if (n < 2048) v = bdc[n - 1024];
  else if (n < 2112) v = bv[n - 2048];
  else               v = bq[n - 2112];
  biasc[n] = v;
}

// ---------------- fused projection GEMM ----------------
// C[4096,2176] = A[4096,1024](bf16) * Bt[2176,1024]^T(bf16), epilogue by col range.

__global__ __launch_bounds__(256) void k_gemm(const ushort* __restrict__ A,
                                              const ushort* __restrict__ Bt,
                                              const float* __restrict__ bias,
                                              float* __restrict__ C) {
  __shared__ ushort As[128*64];
  __shared__ ushort Bs[128*64];
  int tid = threadIdx.x;
  int w = tid >> 6, l = tid & 63;
  int m0 = blockIdx.y * 128, n0 = blockIdx.x * 128;
  int wr = w >> 1, wc = w & 1;
  f32x4 acc[4][4] = {};
  int srow = w*8 + (l >> 3);
  int scol = (l & 7) * 8;
  int lr = l & 15, lk8 = (l >> 4) * 8;
  for (int k0 = 0; k0 < 1024; k0 += 64) {
    __syncthreads();
    for (int r = 0; r < 4; ++r) {
      __builtin_amdgcn_global_load_lds(
        (const __attribute__((address_space(1))) void*)(A + (size_t)(m0 + r*32 + srow)*1024 + k0 + scol),
        (__attribute__((address_space(3))) void*)(As + r*2048 + w*512), 16, 0, 0);
      __builtin_amdgcn_global_load_lds(
        (const __attribute__((address_space(1))) void*)(Bt + (size_t)(n0 + r*32 + srow)*1024 + k0 + scol),
        (__attribute__((address_space(3))) void*)(Bs + r*2048 + w*512), 16, 0, 0);
    }
    __syncthreads();
    for (int kk = 0; kk < 64; kk += 32) {
      bf16x8 af[4], bfr[4];
#pragma unroll
      for (int i = 0; i < 4; ++i)
        af[i] = *(const bf16x8*)(As + (wr*64 + i*16 + lr)*64 + kk + lk8);
#pragma unroll
      for (int j = 0; j < 4; ++j)
        bfr[j] = *(const bf16x8*)(Bs + (wc*64 + j*16 + lr)*64 + kk + lk8);
#pragma unroll
      for (int i = 0; i < 4; ++i)
#pragma unroll
        for (int j = 0; j < 4; ++j)
          acc[i][j] = __builtin_amdgcn_mfma_f32_16x16x32_bf16(af[i], bfr[j], acc[i][j], 0, 0, 0);
    }
  }
  int epi = (blockIdx.x < 8) ? 0 : ((blockIdx.x < 16) ? 1 : 2);
#pragma unroll
  for (int i = 0; i < 4; ++i)
#pragma unroll
    for (int j = 0; j < 4; ++j) {
      int col = n0 + wc*64 + j*16 + lr;
      int row0 = m0 + wr*64 + i*16 + (l >> 4)*4;
      float bs = bias[col];
#pragma unroll
      for (int r = 0; r < 4; ++r) {
        float v = acc[i][j][r] + bs;
        if (epi == 0)      v = tanhf(v);
        else if (epi == 1) v = 1.0f/(1.0f + expf(-v));
        C[(size_t)(row0 + r)*NCAT + col] = v;
      }
    }
}

// ---------------- recurrence: chunked scan ----------------
// Lane mapping (phases 1 & 3): 16 threads per d, each owns 4 consecutive k.
// Stores are lane-contiguous: block writes 4KB per timestep slab.

__global__ __launch_bounds__(256) void k_phase1(const float* __restrict__ C,
                                                float* __restrict__ Sws,
                                                float* __restrict__ Dp) {
  int bid = blockIdx.x;
  int c = bid >> 9, b = (bid >> 6) & 7, dg = bid & 63;
  int tid = threadIdx.x;
  int d = dg*16 + (tid >> 4), kq = tid & 15;
  f32x4 h = {};
  float dp = 1.0f;
  for (int tl = 0; tl < CLEN; ++tl) {
    int t = c*CLEN + tl;
    const float* Crow = C + ((size_t)t*BATCH + b)*NCAT;
    float de = Crow[1024 + d];
    float ke = Crow[d];
    f32x4 v = ((const f32x4*)(Crow + 2048))[kq];
    h = de*h + ke*v;
    dp *= de;
  }
  ((f32x4*)Sws)[(size_t)c*131072 + ((size_t)b*DM + d)*16 + kq] = h;
  if (kq == 0) Dp[(size_t)(c*BATCH + b)*DM + d] = dp;
}

// Phase 2: scan chunk boundaries. After this, Sws[c] = H at START of chunk c+1.
__global__ __launch_bounds__(256) void k_phase2(const float* __restrict__ H0,
                                                const float* __restrict__ Dp,
                                                float* __restrict__ Sws) {
  int q = blockIdx.x*256 + threadIdx.x;   // float4 index, 0..131071
  int bd = q >> 4;                        // b*1024 + d
  f32x4 h = ((const f32x4*)H0)[q];
  f32x4* S4 = (f32x4*)Sws;
  for (int c = 0; c < NCHUNK; ++c) {
    float dp = Dp[(size_t)c*BATCH*DM + bd];
    size_t idx = (size_t)c*131072 + q;
    h = dp*h + S4[idx];
    S4[idx] = h;
  }
}

// Phase 3: recompute trajectory per chunk in parallel; write H_all + output.
__global__ __launch_bounds__(256) void k_phase3(const float* __restrict__ C,
                                                const float* __restrict__ z,
                                                const float* __restrict__ H0,
                                                const float* __restrict__ Sws,
                                                float* __restrict__ out,
                                                float* __restrict__ Hall) {
  int bid = blockIdx.x;
  int c = bid >> 9, b = (bid >> 6) & 7, dg = bid & 63;
  int tid = threadIdx.x;
  int d = dg*16 + (tid >> 4), kq = tid & 15;
  size_t bd16 = ((size_t)b*DM + d)*16 + kq;   // float4 index within one timestep slab
  f32x4 h = (c == 0) ? ((const f32x4*)H0)[bd16]
                     : ((const f32x4*)Sws)[(size_t)(c-1)*131072 + bd16];
  f32x4* H4 = (f32x4*)Hall;
  if (c == 0) __builtin_nontemporal_store(h, &H4[bd16]);   // t=0 slot is H0
  for (int tl = 0; tl < CLEN; ++tl) {
    int t = c*CLEN + tl;
    size_t row = (size_t)t*BATCH + b;
    const float* Crow = C + row*NCAT;
    float de = Crow[1024 + d];
    float ke = Crow[d];
    f32x4 v = ((const f32x4*)(Crow + 2048))[kq];
    f32x4 q = ((const f32x4*)(Crow + 2048))[16 + kq];
    h = de*h + ke*v;
    float s = h[0]*q[0] + h[1]*q[1] + h[2]*q[2] + h[3]*q[3];
    s += __shfl_xor(s, 1, 16);
    s += __shfl_xor(s, 2, 16);
    s += __shfl_xor(s, 4, 16);
    s += __shfl_xor(s, 8, 16);
    if (kq == 0) {
      float zz = z[row*DM + d];
      float sig = 1.0f/(1.0f + __expf(-zz));
      __builtin_nontemporal_store(s * zz * sig, &out[row*DM + d]);
    }
    __builtin_nontemporal_store(h, &H4[(size_t)(t+1)*131072 + bd16]);
  }
}

// ---------------- launcher ----------------

extern "C" void kernel_launch(void* const* d_in, const int* in_sizes, int n_in,
                              void* d_out, int out_size, void* d_ws, size_t ws_size,
                              hipStream_t stream) {
  const float* x  = (const float*)d_in[0];
  const float* z  = (const float*)d_in[1];
  const float* H0 = (const float*)d_in[2];
  const float* Wk = (const float*)d_in[3];
  const float* bk = (const float*)d_in[4];
  const float* Wv = (const float*)d_in[5];
  const float* bv = (const float*)d_in[6];
  const float* Wq = (const float*)d_in[7];
  const float* bq = (const float*)d_in[8];
  const float* Wd = (const float*)d_in[9];
  const float* bd = (const float*)d_in[10];

  float* out  = (float*)d_out;                       // [512*8*1024]
  float* Hall = out + (size_t)TSTEPS*BATCH*DM;       // [513*8*1024*64]

  char* ws = (char*)d_ws;
  size_t off = 0;
  ushort* xb   = (ushort*)(ws + off); off += (size_t)MROWS*DM*2;            // 8 MB
  ushort* Wcat = (ushort*)(ws + off); off += (size_t)NCAT*DM*2;             // 4.25 MB
  float* biasc = (float*)(ws + off);  off += (size_t)NCAT*4; off = (off + 255) & ~(size_t)255;
  float* C     = (float*)(ws + off);  off += (size_t)MROWS*NCAT*4;          // 34 MB
  float* Sws   = (float*)(ws + off);  off += (size_t)NCHUNK*BATCH*DM*DK*4;  // 32 MB
  float* Dp    = (float*)(ws + off);  off += (size_t)NCHUNK*BATCH*DM*4;     // 0.5 MB
  if (off > ws_size) return;  // workspace too small -> fail validation cleanly

  k_prep<<<4233, 256, 0, stream>>>(x, xb, Wk, Wd, Wv, Wq, Wcat, bk, bd, bv, bq, biasc);
  k_gemm<<<dim3(17,32), 256, 0, stream>>>(xb, Wcat, biasc, C);
  k_phase1<<<NCHUNK*BATCH*64, 256, 0, stream>>>(C, Sws, Dp);
  k_phase2<<<512, 256, 0, stream>>>(H0, Dp, Sws);
  k_phase3<<<NCHUNK*BATCH*64, 256, 0, stream>>>(C, z, H0, Sws, out, Hall);
}

// Round 4
// 297.845 us; speedup vs baseline: 1.1423x; 1.1423x over previous
//
#include <hip/hip_runtime.h>
#include <stdint.h>

#define TSTEPS 512
#define BATCH 8
#define DM 1024
#define DK 64
#define MROWS (TSTEPS*BATCH)   // 4096
#define NCAT 2176              // 1024 key | 1024 decay | 64 value | 64 query
#define NCHUNK 16
#define CLEN 32                // 512/16

typedef __attribute__((ext_vector_type(8))) __bf16 bf16x8;
typedef __attribute__((ext_vector_type(4))) float f32x4;

__device__ __forceinline__ unsigned short f2bf(float f) {
  unsigned int u = __float_as_uint(f);
  u += 0x7fffu + ((u >> 16) & 1u);
  return (unsigned short)(u >> 16);
}

// ---------------- unified prep kernel ----------------
// grid layout (1-D, 256 threads each):
//   [0,2048)      convert x -> bf16 (8 elems/thread)
//   [2048,3072)   transpose Wk  (32x32 tiles, rowOff 0)
//   [3072,4096)   transpose Wd  (rowOff 1024)
//   [4096,4160)   transpose Wv  (rowOff 2048)
//   [4160,4224)   transpose Wq  (rowOff 2112)
//   [4224,4233)   bias concat
__global__ __launch_bounds__(256) void k_prep(const float* __restrict__ x,
                                              ushort* __restrict__ xb,
                                              const float* __restrict__ Wk,
                                              const float* __restrict__ Wd,
                                              const float* __restrict__ Wv,
                                              const float* __restrict__ Wq,
                                              ushort* __restrict__ Wcat,
                                              const float* __restrict__ bk,
                                              const float* __restrict__ bdc,
                                              const float* __restrict__ bv,
                                              const float* __restrict__ bq,
                                              float* __restrict__ biasc) {
  __shared__ float s[32][33];
  int bid = blockIdx.x, tid = threadIdx.x;
  if (bid < 2048) {
    int i = bid * 256 + tid;             // 524288 total
    const float4* x4 = (const float4*)x;
    float4 a = x4[2*i], b = x4[2*i+1];
    union { ushort ss[8]; uint4 v; } o;
    o.ss[0]=f2bf(a.x); o.ss[1]=f2bf(a.y); o.ss[2]=f2bf(a.z); o.ss[3]=f2bf(a.w);
    o.ss[4]=f2bf(b.x); o.ss[5]=f2bf(b.y); o.ss[6]=f2bf(b.z); o.ss[7]=f2bf(b.w);
    ((uint4*)xb)[i] = o.v;
    return;
  }
  if (bid < 4224) {
    const float* src; int rel, lg, rowOff;
    size_t N;
    if (bid < 3072)      { src = Wk; N = 1024; lg = 5; rowOff = 0;    rel = bid - 2048; }
    else if (bid < 4096) { src = Wd; N = 1024; lg = 5; rowOff = 1024; rel = bid - 3072; }
    else if (bid < 4160) { src = Wv; N = 64;   lg = 1; rowOff = 2048; rel = bid - 4096; }
    else                 { src = Wq; N = 64;   lg = 1; rowOff = 2112; rel = bid - 4160; }
    int n0 = (rel & ((1 << lg) - 1)) << 5;
    int k0 = (rel >> lg) << 5;
    int tx = tid & 31, ty = tid >> 5;    // 32 x 8
    for (int i = 0; i < 4; ++i)
      s[ty + 8*i][tx] = src[(size_t)(k0 + ty + 8*i) * N + n0 + tx];
    __syncthreads();
    for (int i = 0; i < 4; ++i)
      Wcat[(size_t)(n0 + ty + 8*i + rowOff) * 1024 + k0 + tx] = f2bf(s[tx][ty + 8*i]);
    return;
  }
  int n = (bid - 4224) * 256 + tid;
  if (n >= NCAT) return;
  float v;
  if (n < 1024)      v = bk[n];
  else if (n < 2048) v = bdc[n - 1024];
  else if (n < 2112) v = bv[n - 2048];
  else               v = bq[n - 2112];
  biasc[n] = v;
}

// ---------------- fused projection GEMM ----------------
// C[4096,2176] = A[4096,1024](bf16) * Bt[2176,1024]^T(bf16), epilogue by col range.

__global__ __launch_bounds__(256) void k_gemm(const ushort* __restrict__ A,
                                              const ushort* __restrict__ Bt,
                                              const float* __restrict__ bias,
                                              float* __restrict__ C) {
  __shared__ ushort As[128*64];
  __shared__ ushort Bs[128*64];
  int tid = threadIdx.x;
  int w = tid >> 6, l = tid & 63;
  int m0 = blockIdx.y * 128, n0 = blockIdx.x * 128;
  int wr = w >> 1, wc = w & 1;
  f32x4 acc[4][4] = {};
  int srow = w*8 + (l >> 3);
  int scol = (l & 7) * 8;
  int lr = l & 15, lk8 = (l >> 4) * 8;
  for (int k0 = 0; k0 < 1024; k0 += 64) {
    __syncthreads();
    for (int r = 0; r < 4; ++r) {
      __builtin_amdgcn_global_load_lds(
        (const __attribute__((address_space(1))) void*)(A + (size_t)(m0 + r*32 + srow)*1024 + k0 + scol),
        (__attribute__((address_space(3))) void*)(As + r*2048 + w*512), 16, 0, 0);
      __builtin_amdgcn_global_load_lds(
        (const __attribute__((address_space(1))) void*)(Bt + (size_t)(n0 + r*32 + srow)*1024 + k0 + scol),
        (__attribute__((address_space(3))) void*)(Bs + r*2048 + w*512), 16, 0, 0);
    }
    __syncthreads();
    for (int kk = 0; kk < 64; kk += 32) {
      bf16x8 af[4], bfr[4];
#pragma unroll
      for (int i = 0; i < 4; ++i)
        af[i] = *(const bf16x8*)(As + (wr*64 + i*16 + lr)*64 + kk + lk8);
#pragma unroll
      for (int j = 0; j < 4; ++j)
        bfr[j] = *(const bf16x8*)(Bs + (wc*64 + j*16 + lr)*64 + kk + lk8);
#pragma unroll
      for (int i = 0; i < 4; ++i)
#pragma unroll
        for (int j = 0; j < 4; ++j)
          acc[i][j] = __builtin_amdgcn_mfma_f32_16x16x32_bf16(af[i], bfr[j], acc[i][j], 0, 0, 0);
    }
  }
  int epi = (blockIdx.x < 8) ? 0 : ((blockIdx.x < 16) ? 1 : 2);
#pragma unroll
  for (int i = 0; i < 4; ++i)
#pragma unroll
    for (int j = 0; j < 4; ++j) {
      int col = n0 + wc*64 + j*16 + lr;
      int row0 = m0 + wr*64 + i*16 + (l >> 4)*4;
      float bs = bias[col];
#pragma unroll
      for (int r = 0; r < 4; ++r) {
        float v = acc[i][j][r] + bs;
        if (epi == 0)      v = tanhf(v);
        else if (epi == 1) v = 1.0f/(1.0f + expf(-v));
        C[(size_t)(row0 + r)*NCAT + col] = v;
      }
    }
}

// ---------------- recurrence: chunked scan ----------------
// Lane mapping (phases 1 & 3): 16 threads per d, each owns 4 consecutive k.
// Stores are lane-contiguous: block writes 4KB per timestep slab.

// Phase 1: per chunk, local state from zero + decay product. Chunk 15 skipped
// (its local state is only consumed through phase2's scan, whose post-c=14
// output is never read).
__global__ __launch_bounds__(256) void k_phase1(const float* __restrict__ C,
                                                float* __restrict__ Sws,
                                                float* __restrict__ Dp) {
  int bid = blockIdx.x;
  int c = bid >> 9, b = (bid >> 6) & 7, dg = bid & 63;
  int tid = threadIdx.x;
  int d = dg*16 + (tid >> 4), kq = tid & 15;
  f32x4 h = {};
  float dp = 1.0f;
  for (int tl = 0; tl < CLEN; ++tl) {
    int t = c*CLEN + tl;
    const float* Crow = C + ((size_t)t*BATCH + b)*NCAT;
    float de = Crow[1024 + d];
    float ke = Crow[d];
    f32x4 v = ((const f32x4*)(Crow + 2048))[kq];
    h = de*h + ke*v;
    dp *= de;
  }
  ((f32x4*)Sws)[(size_t)c*131072 + ((size_t)b*DM + d)*16 + kq] = h;
  if (kq == 0) Dp[(size_t)(c*BATCH + b)*DM + d] = dp;
}

// Phase 2: scan chunk boundaries. After this, Sws[c] = H at START of chunk c+1,
// for c = 0..14 (Sws[15] never read).
__global__ __launch_bounds__(256) void k_phase2(const float* __restrict__ H0,
                                                const float* __restrict__ Dp,
                                                float* __restrict__ Sws) {
  int q = blockIdx.x*256 + threadIdx.x;   // float4 index, 0..131071
  int bd = q >> 4;                        // b*1024 + d
  f32x4 h = ((const f32x4*)H0)[q];
  f32x4* S4 = (f32x4*)Sws;
  for (int c = 0; c < NCHUNK - 1; ++c) {
    float dp = Dp[(size_t)c*BATCH*DM + bd];
    size_t idx = (size_t)c*131072 + q;
    h = dp*h + S4[idx];
    S4[idx] = h;
  }
}

// Phase 3: recompute trajectory per chunk in parallel; write H_all + output.
__global__ __launch_bounds__(256) void k_phase3(const float* __restrict__ C,
                                                const float* __restrict__ z,
                                                const float* __restrict__ H0,
                                                const float* __restrict__ Sws,
                                                float* __restrict__ out,
                                                float* __restrict__ Hall) {
  int bid = blockIdx.x;
  int c = bid >> 9, b = (bid >> 6) & 7, dg = bid & 63;
  int tid = threadIdx.x;
  int d = dg*16 + (tid >> 4), kq = tid & 15;
  size_t bd16 = ((size_t)b*DM + d)*16 + kq;   // float4 index within one timestep slab
  f32x4 h = (c == 0) ? ((const f32x4*)H0)[bd16]
                     : ((const f32x4*)Sws)[(size_t)(c-1)*131072 + bd16];
  f32x4* H4 = (f32x4*)Hall;
  if (c == 0) __builtin_nontemporal_store(h, &H4[bd16]);   // t=0 slot is H0
  for (int tl = 0; tl < CLEN; ++tl) {
    int t = c*CLEN + tl;
    size_t row = (size_t)t*BATCH + b;
    const float* Crow = C + row*NCAT;
    float de = Crow[1024 + d];
    float ke = Crow[d];
    f32x4 v = ((const f32x4*)(Crow + 2048))[kq];
    f32x4 q = ((const f32x4*)(Crow + 2048))[16 + kq];
    h = de*h + ke*v;
    float s = h[0]*q[0] + h[1]*q[1] + h[2]*q[2] + h[3]*q[3];
    s += __shfl_xor(s, 1, 16);
    s += __shfl_xor(s, 2, 16);
    s += __shfl_xor(s, 4, 16);
    s += __shfl_xor(s, 8, 16);
    if (kq == 0) {
      float zz = z[row*DM + d];
      float sig = 1.0f/(1.0f + __expf(-zz));
      out[row*DM + d] = s * zz * sig;   // cached store: L2 merges 4B/lane writes
    }
    __builtin_nontemporal_store(h, &H4[(size_t)(t+1)*131072 + bd16]);
  }
}

// ---------------- launcher ----------------

extern "C" void kernel_launch(void* const* d_in, const int* in_sizes, int n_in,
                              void* d_out, int out_size, void* d_ws, size_t ws_size,
                              hipStream_t stream) {
  const float* x  = (const float*)d_in[0];
  const float* z  = (const float*)d_in[1];
  const float* H0 = (const float*)d_in[2];
  const float* Wk = (const float*)d_in[3];
  const float* bk = (const float*)d_in[4];
  const float* Wv = (const float*)d_in[5];
  const float* bv = (const float*)d_in[6];
  const float* Wq = (const float*)d_in[7];
  const float* bq = (const float*)d_in[8];
  const float* Wd = (const float*)d_in[9];
  const float* bd = (const float*)d_in[10];

  float* out  = (float*)d_out;                       // [512*8*1024]
  float* Hall = out + (size_t)TSTEPS*BATCH*DM;       // [513*8*1024*64]

  char* ws = (char*)d_ws;
  size_t off = 0;
  ushort* xb   = (ushort*)(ws + off); off += (size_t)MROWS*DM*2;            // 8 MB
  ushort* Wcat = (ushort*)(ws + off); off += (size_t)NCAT*DM*2;             // 4.25 MB
  float* biasc = (float*)(ws + off);  off += (size_t)NCAT*4; off = (off + 255) & ~(size_t)255;
  float* C     = (float*)(ws + off);  off += (size_t)MROWS*NCAT*4;          // 34 MB
  float* Sws   = (float*)(ws + off);  off += (size_t)NCHUNK*BATCH*DM*DK*4;  // 32 MB
  float* Dp    = (float*)(ws + off);  off += (size_t)NCHUNK*BATCH*DM*4;     // 0.5 MB
  if (off > ws_size) return;  // workspace too small -> fail validation cleanly

  k_prep<<<4233, 256, 0, stream>>>(x, xb, Wk, Wd, Wv, Wq, Wcat, bk, bd, bv, bq, biasc);
  k_gemm<<<dim3(17,32), 256, 0, stream>>>(xb, Wcat, biasc, C);
  k_phase1<<<(NCHUNK-1)*BATCH*64, 256, 0, stream>>>(C, Sws, Dp);
  k_phase2<<<512, 256, 0, stream>>>(H0, Dp, Sws);
  k_phase3<<<NCHUNK*BATCH*64, 256, 0, stream>>>(C, z, H0, Sws, out, Hall);
}